// Round 9
// baseline (494.705 us; speedup 1.0000x reference)
//
#include <hip/hip_runtime.h>
#include <hip/hip_fp16.h>

// 2-layer GCN, N=100000, E=3200000, feats 512 -> 16 -> 40.
// out[d] = dinv[d]*(sum_{s->d} h[s]*dinv[s] + h[d]*dinv[d]) + b,  dinv = rsqrt(deg+1)
//
// Round-9: edge kernels re-tuned for occupancy + VMEM request width.
//  * agg: 2 lanes/node, f16x8 (16B) gathers -> 32 rows per wave-instr, 8x fewer
//    gather instrs, 8x less esrc redundancy (was 16 lanes/node, 4 rows/instr).
//  * k_part: 1024 blocks (was 256 = 1 block/CU).
//  * k_sortb: 1024 threads/block (was 256; 4x less serial depth per bucket).
//  * gemm1 (MFMA), CSR-build pipeline otherwise unchanged from round 6/8.

#define NFEAT_IN 512
#define NF1 16
#define NF2 40
#define BK_LG 8           // 256 nodes per bucket
#define TILE 4096         // edges per partition tile
#define XSTR 264          // xs row stride in halfs
#define WSTR 520          // Wt row stride in halfs

typedef _Float16 f16x8 __attribute__((ext_vector_type(8)));
typedef _Float16 f16x4 __attribute__((ext_vector_type(4)));
typedef float f32x4 __attribute__((ext_vector_type(4)));

// ---------------- per-bucket edge histogram ----------------
__global__ void k_bhist(const int* __restrict__ dst, int* __restrict__ gbsz, int E, int nbk) {
  __shared__ int h[512];
  for (int i = threadIdx.x; i < nbk; i += 256) h[i] = 0;
  __syncthreads();
  int stride = gridDim.x * 256;
  for (int e = blockIdx.x * 256 + threadIdx.x; e < E; e += stride)
    atomicAdd(&h[dst[e] >> BK_LG], 1);
  __syncthreads();
  for (int i = threadIdx.x; i < nbk; i += 256)
    if (h[i]) atomicAdd(&gbsz[i], h[i]);
}

// ---------------- scan bucket sizes (nbk <= 512), one block ----------------
__global__ void k_scanb(const int* __restrict__ gbsz, int* __restrict__ boff,
                        int* __restrict__ gcur, int* __restrict__ rp,
                        int nbk, int n, int E) {
  __shared__ int s[512];
  int t = threadIdx.x;
  s[t] = (t < nbk) ? gbsz[t] : 0;
  __syncthreads();
  for (int o = 1; o < 512; o <<= 1) {
    int v = (t >= o) ? s[t - o] : 0;
    __syncthreads();
    s[t] += v;
    __syncthreads();
  }
  if (t < nbk) {
    int ex = s[t] - gbsz[t];
    boff[t] = ex;
    gcur[t] = ex;
  }
  if (t == 0) { boff[nbk] = E; rp[n] = E; }
}

// ---------------- bucket partition: ebuf[] = (dst&255)<<17 | src ----------------
__global__ void k_part(const int* __restrict__ src, const int* __restrict__ dst,
                       int* __restrict__ gcur, unsigned int* __restrict__ ebuf,
                       int E, int nbk) {
  __shared__ int hist[512];
  __shared__ int hbase[512];
  int chunk = (E + gridDim.x - 1) / gridDim.x;
  int beg = blockIdx.x * chunk;
  int end = min(E, beg + chunk);
  for (int t0 = beg; t0 < end; t0 += TILE) {
    int t1 = min(end, t0 + TILE);
    for (int i = threadIdx.x; i < nbk; i += 256) hist[i] = 0;
    __syncthreads();
    for (int i = t0 + threadIdx.x; i < t1; i += 256)
      atomicAdd(&hist[dst[i] >> BK_LG], 1);
    __syncthreads();
    for (int i = threadIdx.x; i < nbk; i += 256) {
      int c = hist[i];
      hbase[i] = c ? atomicAdd(&gcur[i], c) : 0;
      hist[i] = 0;  // becomes rank counter
    }
    __syncthreads();
    for (int i = t0 + threadIdx.x; i < t1; i += 256) {
      int d = dst[i];
      int b = d >> BK_LG;
      int r = atomicAdd(&hist[b], 1);
      ebuf[hbase[b] + r] = ((unsigned)(d & ((1 << BK_LG) - 1)) << 17) | (unsigned)src[i];
    }
    __syncthreads();
  }
}

// ---------------- per-bucket sort to CSR + deg/dinv/rp (1024 threads) ----------------
__global__ __launch_bounds__(1024) void k_sortb(
    const unsigned int* __restrict__ ebuf, const int* __restrict__ boff,
    int* __restrict__ esrc, int* __restrict__ rp, float* __restrict__ dinv,
    int n) {
  __shared__ int hist[256];
  __shared__ int scan[256];
  __shared__ int cur[256];
  int b = blockIdx.x;
  int tid = threadIdx.x;
  int e0 = boff[b], e1 = boff[b + 1];
  if (tid < 256) hist[tid] = 0;
  __syncthreads();
  for (int e = e0 + tid; e < e1; e += 1024)
    atomicAdd(&hist[ebuf[e] >> 17], 1);
  __syncthreads();
  if (tid < 256) scan[tid] = hist[tid];
  __syncthreads();
  for (int o = 1; o < 256; o <<= 1) {
    int v = (tid < 256 && tid >= o) ? scan[tid - o] : 0;
    __syncthreads();
    if (tid < 256) scan[tid] += v;
    __syncthreads();
  }
  if (tid < 256) {
    int excl = scan[tid] - hist[tid];
    cur[tid] = e0 + excl;
    int vg = (b << BK_LG) + tid;
    if (vg < n) {
      rp[vg] = e0 + excl;
      dinv[vg] = rsqrtf((float)(hist[tid] + 1));  // +1 self-loop
    }
  }
  __syncthreads();
  for (int e = e0 + tid; e < e1; e += 1024) {
    unsigned p = ebuf[e];
    int pos = atomicAdd(&cur[p >> 17], 1);
    esrc[pos] = (int)(p & 0x1FFFF);
  }
}

// ---------------- layer-1 gemm via MFMA (unchanged) ----------------
__global__ __launch_bounds__(256) void k_gemm1(
    const float* __restrict__ x, const float* __restrict__ W1,
    const float* __restrict__ dinv, __half* __restrict__ h1s, int ntiles) {
  __shared__ _Float16 Wt[NF1 * WSTR];
  __shared__ _Float16 xs[4][16 * XSTR];
  for (int i = threadIdx.x; i < NFEAT_IN * NF1; i += 256) {
    int k = i >> 4, f = i & 15;
    Wt[f * WSTR + k] = (_Float16)W1[i];
  }
  __syncthreads();
  int w = threadIdx.x >> 6;
  int l = threadIdx.x & 63;
  int tile = blockIdx.x * 4 + w;
  if (tile >= ntiles) return;
  int v0 = tile << 4;
  int fr = l & 15;
  int kb = l >> 4;
  _Float16* xsw = &xs[w][0];
  const _Float16* xrow = &xsw[fr * XSTR + (kb << 3)];
  const _Float16* wrow = &Wt[fr * WSTR + (kb << 3)];
  f32x4 acc = {0.f, 0.f, 0.f, 0.f};
#pragma unroll
  for (int half = 0; half < 2; ++half) {
#pragma unroll
    for (int i = 0; i < 16; ++i) {
      float4 a = *(const float4*)&x[(size_t)(v0 + i) * NFEAT_IN + half * 256 + l * 4];
      f16x4 hv = {(_Float16)a.x, (_Float16)a.y, (_Float16)a.z, (_Float16)a.w};
      *(f16x4*)&xsw[i * XSTR + l * 4] = hv;
    }
#pragma unroll
    for (int kk = 0; kk < 8; ++kk) {
      f16x8 av = *(const f16x8*)&xrow[kk * 32];
      f16x8 bv = *(const f16x8*)&wrow[half * 256 + kk * 32];
      acc = __builtin_amdgcn_mfma_f32_16x16x32_f16(av, bv, acc, 0, 0, 0);
    }
  }
  int rbase = kb << 2;
#pragma unroll
  for (int q = 0; q < 4; ++q) {
    int v = v0 + rbase + q;
    h1s[(size_t)v * NF1 + fr] = __float2half(acc[q] * dinv[v]);
  }
}

// ---------------- layer-1 agg: 2 lanes/node, f16x8 gathers ----------------
__global__ __launch_bounds__(256) void k_agg1(
    const int* __restrict__ rp, const int* __restrict__ esrc,
    const __half* __restrict__ h, const float* __restrict__ dinv,
    const float* __restrict__ b1, __half* __restrict__ as2, int n2) {
  int t = blockIdx.x * 256 + threadIdx.x;
  if (t >= n2) return;
  int v = t >> 1, hw = t & 1;
  int beg = rp[v], end = rp[v + 1];
  const f16x8* hp = (const f16x8*)h;  // node row = 2 chunks of 8 halfs
  f16x8 sv = hp[(size_t)v * 2 + hw];  // self-loop
  float sum[8];
#pragma unroll
  for (int j = 0; j < 8; ++j) sum[j] = (float)sv[j];
  int e = beg;
  for (; e + 4 <= end; e += 4) {
    int s0 = esrc[e], s1 = esrc[e + 1], s2 = esrc[e + 2], s3 = esrc[e + 3];
    f16x8 r0 = hp[(size_t)s0 * 2 + hw];
    f16x8 r1 = hp[(size_t)s1 * 2 + hw];
    f16x8 r2 = hp[(size_t)s2 * 2 + hw];
    f16x8 r3 = hp[(size_t)s3 * 2 + hw];
#pragma unroll
    for (int j = 0; j < 8; ++j)
      sum[j] += ((float)r0[j] + (float)r1[j]) + ((float)r2[j] + (float)r3[j]);
  }
  for (; e < end; ++e) {
    f16x8 r = hp[(size_t)esrc[e] * 2 + hw];
#pragma unroll
    for (int j = 0; j < 8; ++j) sum[j] += (float)r[j];
  }
  float dv = dinv[v];
  const float4* b1p = (const float4*)b1;
  float4 bA = b1p[hw * 2], bB = b1p[hw * 2 + 1];
  float bb[8] = {bA.x, bA.y, bA.z, bA.w, bB.x, bB.y, bB.z, bB.w};
  f16x8 o;
#pragma unroll
  for (int j = 0; j < 8; ++j) {
    float a = fmaf(dv, sum[j], bb[j]);
    o[j] = (_Float16)((a > 0.f ? a : 0.f) * dv);
  }
  ((f16x8*)as2)[(size_t)v * 2 + hw] = o;
}

// ---------------- layer-2 agg + W2 + b2 + log_softmax (2 lanes/node) ----------------
#define SASTR 17
__global__ __launch_bounds__(256) void k_agg2fin(
    const int* __restrict__ rp, const int* __restrict__ esrc,
    const __half* __restrict__ h, const float* __restrict__ dinv,
    const float* __restrict__ W2, const float* __restrict__ b2,
    float* __restrict__ out, int n2) {
  __shared__ float W2s[NF1 * NF2];
  __shared__ float b2s[NF2];
  __shared__ float sa[128 * SASTR];  // 128 nodes/block, padded stride
  for (int i = threadIdx.x; i < NF1 * NF2; i += 256) W2s[i] = W2[i];
  if (threadIdx.x < NF2) b2s[threadIdx.x] = b2[threadIdx.x];
  int t = blockIdx.x * 256 + threadIdx.x;
  int v = t >> 1, hw = t & 1, nl = threadIdx.x >> 1;
  bool valid = t < n2;
  if (valid) {
    int beg = rp[v], end = rp[v + 1];
    const f16x8* hp = (const f16x8*)h;
    f16x8 sv = hp[(size_t)v * 2 + hw];
    float sum[8];
#pragma unroll
    for (int j = 0; j < 8; ++j) sum[j] = (float)sv[j];
    int e = beg;
    for (; e + 4 <= end; e += 4) {
      int s0 = esrc[e], s1 = esrc[e + 1], s2 = esrc[e + 2], s3 = esrc[e + 3];
      f16x8 r0 = hp[(size_t)s0 * 2 + hw];
      f16x8 r1 = hp[(size_t)s1 * 2 + hw];
      f16x8 r2 = hp[(size_t)s2 * 2 + hw];
      f16x8 r3 = hp[(size_t)s3 * 2 + hw];
#pragma unroll
      for (int j = 0; j < 8; ++j)
        sum[j] += ((float)r0[j] + (float)r1[j]) + ((float)r2[j] + (float)r3[j]);
    }
    for (; e < end; ++e) {
      f16x8 r = hp[(size_t)esrc[e] * 2 + hw];
#pragma unroll
      for (int j = 0; j < 8; ++j) sum[j] += (float)r[j];
    }
    float dv = dinv[v];
#pragma unroll
    for (int j = 0; j < 8; ++j) sa[nl * SASTR + hw * 8 + j] = dv * sum[j];
  }
  __syncthreads();
  if (!valid) return;
  const float* av = &sa[nl * SASTR];
  float z[20];
  float m = -1e30f;
#pragma unroll
  for (int j = 0; j < 20; ++j) {
    int g = hw * 20 + j;
    float acc = b2s[g];
#pragma unroll
    for (int ff = 0; ff < NF1; ++ff) acc = fmaf(av[ff], W2s[ff * NF2 + g], acc);
    z[j] = acc;
    m = fmaxf(m, acc);
  }
  m = fmaxf(m, __shfl_xor(m, 1, 2));
  float s = 0.f;
#pragma unroll
  for (int j = 0; j < 20; ++j) s += __expf(z[j] - m);
  s += __shfl_xor(s, 1, 2);
  float ls = m + __logf(s);
  float4* orow = (float4*)(out + (size_t)v * NF2 + hw * 20);
#pragma unroll
  for (int q = 0; q < 5; ++q)
    orow[q] = make_float4(z[4 * q] - ls, z[4 * q + 1] - ls,
                          z[4 * q + 2] - ls, z[4 * q + 3] - ls);
}

extern "C" void kernel_launch(void* const* d_in, const int* in_sizes, int n_in,
                              void* d_out, int out_size, void* d_ws, size_t ws_size,
                              hipStream_t stream) {
  const float* x  = (const float*)d_in[0];
  const int*   ei = (const int*)d_in[1];
  const float* W1 = (const float*)d_in[2];
  const float* b1 = (const float*)d_in[3];
  const float* W2 = (const float*)d_in[4];
  const float* b2 = (const float*)d_in[5];
  int n = in_sizes[0] / NFEAT_IN;  // 100000
  int E = in_sizes[1] / 2;         // 3200000
  const int* src = ei;
  const int* dst = ei + E;
  float* out = (float*)d_out;
  int nbk = ((n - 1) >> BK_LG) + 1;   // 391
  int ntiles = n >> 4;                // 6250
  int n2 = n * 2;

  char* ws = (char*)d_ws;
  size_t off = 0;
  auto alloc = [&](size_t bytes) { size_t o = off; off = (off + bytes + 63) & ~63ULL; return o; };
  int*   gbsz = (int*)(ws + alloc(512 * 4));
  int*   boff = (int*)(ws + alloc(513 * 4));
  int*   gcur = (int*)(ws + alloc(512 * 4));
  int*   rp   = (int*)(ws + alloc((size_t)(n + 1) * 4));
  float* dinv = (float*)(ws + alloc((size_t)n * 4));
  unsigned int* ebuf = (unsigned int*)(ws + alloc((size_t)E * 4));
  int*   esrc = (int*)(ws + alloc((size_t)E * 4));
  __half* h1s = (__half*)(ws + alloc((size_t)n * NF1 * 2));
  __half* as2 = (__half*)(ws + alloc((size_t)n * NF1 * 2));

  hipMemsetAsync(gbsz, 0, 512 * 4, stream);

  k_bhist<<<1024, 256, 0, stream>>>(dst, gbsz, E, nbk);
  k_scanb<<<1, 512, 0, stream>>>(gbsz, boff, gcur, rp, nbk, n, E);
  k_part <<<1024, 256, 0, stream>>>(src, dst, gcur, ebuf, E, nbk);
  k_sortb<<<nbk, 1024, 0, stream>>>(ebuf, boff, esrc, rp, dinv, n);
  k_gemm1<<<(ntiles + 3) / 4, 256, 0, stream>>>(x, W1, dinv, h1s, ntiles);
  k_agg1 <<<(n2 + 255) / 256, 256, 0, stream>>>(rp, esrc, h1s, dinv, b1, as2, n2);
  k_agg2fin<<<(n2 + 255) / 256, 256, 0, stream>>>(rp, esrc, as2, dinv, W2, b2, out, n2);
}

// Round 10
// 465.195 us; speedup vs baseline: 1.0634x; 1.0634x over previous
//
#include <hip/hip_runtime.h>
#include <hip/hip_fp16.h>

// 2-layer GCN, N=100000, E=3200000, feats 512 -> 16 -> 40.
// out[d] = dinv[d]*(sum_{s->d} h[s]*dinv[s] + h[d]*dinv[d]) + b,  dinv = rsqrt(deg+1)
//
// Round-10: cut redundant memory passes.
//  * gemm1: A-fragments loaded DIRECT from global (contiguous 32B/lane matches
//    the 16x16x32 A map) -- no x LDS staging, only W1 (16KB) in LDS.
//  * part/sortb: single-read versions -- rank comes from the pass-1 atomicAdd,
//    edges held in fixed-index register arrays (no dynamic indexing -> no scratch).
//  * agg: unroll 8 (restore r5 MLP depth) in the 2-lane/node f16x8 layout.

#define NFEAT_IN 512
#define NF1 16
#define NF2 40
#define BK_LG 8           // 256 nodes per bucket
#define WSTR 520          // Wt row stride in halfs (512+8)
#define PEPT 16           // part: edges per thread per tile
#define SEPT 16           // sortb: max edges per thread

typedef _Float16 f16x8 __attribute__((ext_vector_type(8)));
typedef float f32x4 __attribute__((ext_vector_type(4)));

// ---------------- per-bucket edge histogram ----------------
__global__ void k_bhist(const int* __restrict__ dst, int* __restrict__ gbsz, int E, int nbk) {
  __shared__ int h[512];
  for (int i = threadIdx.x; i < nbk; i += 256) h[i] = 0;
  __syncthreads();
  int stride = gridDim.x * 256;
  for (int e = blockIdx.x * 256 + threadIdx.x; e < E; e += stride)
    atomicAdd(&h[dst[e] >> BK_LG], 1);
  __syncthreads();
  for (int i = threadIdx.x; i < nbk; i += 256)
    if (h[i]) atomicAdd(&gbsz[i], h[i]);
}

// ---------------- scan bucket sizes (nbk <= 512), one block ----------------
__global__ void k_scanb(const int* __restrict__ gbsz, int* __restrict__ boff,
                        int* __restrict__ gcur, int* __restrict__ rp,
                        int nbk, int n, int E) {
  __shared__ int s[512];
  int t = threadIdx.x;
  s[t] = (t < nbk) ? gbsz[t] : 0;
  __syncthreads();
  for (int o = 1; o < 512; o <<= 1) {
    int v = (t >= o) ? s[t - o] : 0;
    __syncthreads();
    s[t] += v;
    __syncthreads();
  }
  if (t < nbk) {
    int ex = s[t] - gbsz[t];
    boff[t] = ex;
    gcur[t] = ex;
  }
  if (t == 0) { boff[nbk] = E; rp[n] = E; }
}

// ---------------- bucket partition, single edge read ----------------
__global__ __launch_bounds__(256) void k_part(
    const int* __restrict__ src, const int* __restrict__ dst,
    int* __restrict__ gcur, unsigned int* __restrict__ ebuf, int E, int nbk) {
  __shared__ int hist[512];
  __shared__ int hbase[512];
  int chunk = (E + gridDim.x - 1) / gridDim.x;
  int beg = blockIdx.x * chunk;
  int end = min(E, beg + chunk);
  for (int t0 = beg; t0 < end; t0 += PEPT * 256) {
    int t1 = min(end, t0 + PEPT * 256);
    for (int i = threadIdx.x; i < nbk; i += 256) hist[i] = 0;
    __syncthreads();
    unsigned pk[PEPT];
    int bk[PEPT], rk[PEPT];
#pragma unroll
    for (int i = 0; i < PEPT; ++i) {
      int idx = t0 + i * 256 + threadIdx.x;
      bk[i] = -1;
      if (idx < t1) {
        int d = dst[idx];
        int b = d >> BK_LG;
        bk[i] = b;
        pk[i] = ((unsigned)(d & ((1 << BK_LG) - 1)) << 17) | (unsigned)src[idx];
        rk[i] = atomicAdd(&hist[b], 1);  // rank within tile-bucket
      }
    }
    __syncthreads();
    for (int i = threadIdx.x; i < nbk; i += 256) {
      int c = hist[i];
      hbase[i] = c ? atomicAdd(&gcur[i], c) : 0;
    }
    __syncthreads();
#pragma unroll
    for (int i = 0; i < PEPT; ++i)
      if (bk[i] >= 0) ebuf[hbase[bk[i]] + rk[i]] = pk[i];
    __syncthreads();
  }
}

// ---------------- per-bucket sort to CSR + deg/dinv/rp, single edge read ----------------
__global__ __launch_bounds__(1024) void k_sortb(
    const unsigned int* __restrict__ ebuf, const int* __restrict__ boff,
    int* __restrict__ esrc, int* __restrict__ rp, float* __restrict__ dinv, int n) {
  __shared__ int hist[256];
  __shared__ int sc[256];
  __shared__ int base[256];
  int b = blockIdx.x, tid = threadIdx.x;
  int e0 = boff[b], e1 = boff[b + 1];
  if (tid < 256) hist[tid] = 0;
  __syncthreads();
  unsigned pk[SEPT];
  int rk[SEPT];
#pragma unroll
  for (int i = 0; i < SEPT; ++i) {
    int e = e0 + i * 1024 + tid;
    rk[i] = -1;
    if (e < e1) {
      unsigned p = ebuf[e];
      pk[i] = p;
      rk[i] = atomicAdd(&hist[p >> 17], 1);  // rank within dst node
    }
  }
  __syncthreads();
  if (tid < 256) sc[tid] = hist[tid];
  __syncthreads();
  for (int o = 1; o < 256; o <<= 1) {
    int v = (tid < 256 && tid >= o) ? sc[tid - o] : 0;
    __syncthreads();
    if (tid < 256) sc[tid] += v;
    __syncthreads();
  }
  if (tid < 256) {
    int excl = sc[tid] - hist[tid];
    base[tid] = e0 + excl;
    int vg = (b << BK_LG) + tid;
    if (vg < n) {
      rp[vg] = e0 + excl;
      dinv[vg] = rsqrtf((float)(hist[tid] + 1));  // +1 self-loop
    }
  }
  __syncthreads();
#pragma unroll
  for (int i = 0; i < SEPT; ++i)
    if (rk[i] >= 0) esrc[base[pk[i] >> 17] + rk[i]] = (int)(pk[i] & 0x1FFFF);
}

// ---------------- layer-1 gemm via MFMA, A direct from global ----------------
// A map (16x16x32): row=l&15, k=(l>>4)*8+j  -> lane reads 32B contiguous of its row.
// B: Wt[f][k] fp16 LDS, col=l&15, same k.  C/D: col=l&15, row=(l>>4)*4+q.
__global__ __launch_bounds__(256) void k_gemm1(
    const float* __restrict__ x, const float* __restrict__ W1,
    const float* __restrict__ dinv, __half* __restrict__ h1s, int ntiles) {
  __shared__ _Float16 Wt[NF1 * WSTR];  // 16.6 KB
  for (int i = threadIdx.x; i < NFEAT_IN * NF1; i += 256) {
    int k = i >> 4, f = i & 15;
    Wt[f * WSTR + k] = (_Float16)W1[i];
  }
  __syncthreads();
  int w = threadIdx.x >> 6, l = threadIdx.x & 63;
  int tile = blockIdx.x * 4 + w;
  if (tile >= ntiles) return;
  int v0 = tile << 4;
  int fr = l & 15, kb = l >> 4;
  const float* xr = x + (size_t)(v0 + fr) * NFEAT_IN + (kb << 3);
  const _Float16* wrow = &Wt[fr * WSTR + (kb << 3)];
  f32x4 acc = {0.f, 0.f, 0.f, 0.f};
#pragma unroll
  for (int ks = 0; ks < 16; ++ks) {
    float4 fa = *(const float4*)&xr[ks * 32];
    float4 fb = *(const float4*)&xr[ks * 32 + 4];
    f16x8 av = {(_Float16)fa.x, (_Float16)fa.y, (_Float16)fa.z, (_Float16)fa.w,
                (_Float16)fb.x, (_Float16)fb.y, (_Float16)fb.z, (_Float16)fb.w};
    f16x8 bv = *(const f16x8*)&wrow[ks * 32];
    acc = __builtin_amdgcn_mfma_f32_16x16x32_f16(av, bv, acc, 0, 0, 0);
  }
  int rbase = kb << 2;
#pragma unroll
  for (int q = 0; q < 4; ++q) {
    int v = v0 + rbase + q;
    h1s[(size_t)v * NF1 + fr] = __float2half(acc[q] * dinv[v]);
  }
}

// ---------------- layer-1 agg: 2 lanes/node, f16x8 gathers, unroll 8 ----------------
__global__ __launch_bounds__(256) void k_agg1(
    const int* __restrict__ rp, const int* __restrict__ esrc,
    const __half* __restrict__ h, const float* __restrict__ dinv,
    const float* __restrict__ b1, __half* __restrict__ as2, int n2) {
  int t = blockIdx.x * 256 + threadIdx.x;
  if (t >= n2) return;
  int v = t >> 1, hw = t & 1;
  int beg = rp[v], end = rp[v + 1];
  const f16x8* hp = (const f16x8*)h;
  f16x8 sv = hp[(size_t)v * 2 + hw];  // self-loop
  float sum[8];
#pragma unroll
  for (int j = 0; j < 8; ++j) sum[j] = (float)sv[j];
  int e = beg;
  for (; e + 8 <= end; e += 8) {
    int s0 = esrc[e],     s1 = esrc[e + 1], s2 = esrc[e + 2], s3 = esrc[e + 3];
    int s4 = esrc[e + 4], s5 = esrc[e + 5], s6 = esrc[e + 6], s7 = esrc[e + 7];
    f16x8 r0 = hp[(size_t)s0 * 2 + hw];
    f16x8 r1 = hp[(size_t)s1 * 2 + hw];
    f16x8 r2 = hp[(size_t)s2 * 2 + hw];
    f16x8 r3 = hp[(size_t)s3 * 2 + hw];
    f16x8 r4 = hp[(size_t)s4 * 2 + hw];
    f16x8 r5 = hp[(size_t)s5 * 2 + hw];
    f16x8 r6 = hp[(size_t)s6 * 2 + hw];
    f16x8 r7 = hp[(size_t)s7 * 2 + hw];
#pragma unroll
    for (int j = 0; j < 8; ++j)
      sum[j] += (((float)r0[j] + (float)r1[j]) + ((float)r2[j] + (float)r3[j])) +
                (((float)r4[j] + (float)r5[j]) + ((float)r6[j] + (float)r7[j]));
  }
  for (; e < end; ++e) {
    f16x8 r = hp[(size_t)esrc[e] * 2 + hw];
#pragma unroll
    for (int j = 0; j < 8; ++j) sum[j] += (float)r[j];
  }
  float dv = dinv[v];
  const float4* b1p = (const float4*)b1;
  float4 bA = b1p[hw * 2], bB = b1p[hw * 2 + 1];
  float bb[8] = {bA.x, bA.y, bA.z, bA.w, bB.x, bB.y, bB.z, bB.w};
  f16x8 o;
#pragma unroll
  for (int j = 0; j < 8; ++j) {
    float a = fmaf(dv, sum[j], bb[j]);
    o[j] = (_Float16)((a > 0.f ? a : 0.f) * dv);
  }
  ((f16x8*)as2)[(size_t)v * 2 + hw] = o;
}

// ---------------- layer-2 agg + W2 + b2 + log_softmax (2 lanes/node) ----------------
#define SASTR 17
__global__ __launch_bounds__(256) void k_agg2fin(
    const int* __restrict__ rp, const int* __restrict__ esrc,
    const __half* __restrict__ h, const float* __restrict__ dinv,
    const float* __restrict__ W2, const float* __restrict__ b2,
    float* __restrict__ out, int n2) {
  __shared__ float W2s[NF1 * NF2];
  __shared__ float b2s[NF2];
  __shared__ float sa[128 * SASTR];
  for (int i = threadIdx.x; i < NF1 * NF2; i += 256) W2s[i] = W2[i];
  if (threadIdx.x < NF2) b2s[threadIdx.x] = b2[threadIdx.x];
  int t = blockIdx.x * 256 + threadIdx.x;
  int v = t >> 1, hw = t & 1, nl = threadIdx.x >> 1;
  bool valid = t < n2;
  if (valid) {
    int beg = rp[v], end = rp[v + 1];
    const f16x8* hp = (const f16x8*)h;
    f16x8 sv = hp[(size_t)v * 2 + hw];
    float sum[8];
#pragma unroll
    for (int j = 0; j < 8; ++j) sum[j] = (float)sv[j];
    int e = beg;
    for (; e + 8 <= end; e += 8) {
      int s0 = esrc[e],     s1 = esrc[e + 1], s2 = esrc[e + 2], s3 = esrc[e + 3];
      int s4 = esrc[e + 4], s5 = esrc[e + 5], s6 = esrc[e + 6], s7 = esrc[e + 7];
      f16x8 r0 = hp[(size_t)s0 * 2 + hw];
      f16x8 r1 = hp[(size_t)s1 * 2 + hw];
      f16x8 r2 = hp[(size_t)s2 * 2 + hw];
      f16x8 r3 = hp[(size_t)s3 * 2 + hw];
      f16x8 r4 = hp[(size_t)s4 * 2 + hw];
      f16x8 r5 = hp[(size_t)s5 * 2 + hw];
      f16x8 r6 = hp[(size_t)s6 * 2 + hw];
      f16x8 r7 = hp[(size_t)s7 * 2 + hw];
#pragma unroll
      for (int j = 0; j < 8; ++j)
        sum[j] += (((float)r0[j] + (float)r1[j]) + ((float)r2[j] + (float)r3[j])) +
                  (((float)r4[j] + (float)r5[j]) + ((float)r6[j] + (float)r7[j]));
    }
    for (; e < end; ++e) {
      f16x8 r = hp[(size_t)esrc[e] * 2 + hw];
#pragma unroll
      for (int j = 0; j < 8; ++j) sum[j] += (float)r[j];
    }
    float dv = dinv[v];
#pragma unroll
    for (int j = 0; j < 8; ++j) sa[nl * SASTR + hw * 8 + j] = dv * sum[j];
  }
  __syncthreads();
  if (!valid) return;
  const float* av = &sa[nl * SASTR];
  float z[20];
  float m = -1e30f;
#pragma unroll
  for (int j = 0; j < 20; ++j) {
    int g = hw * 20 + j;
    float acc = b2s[g];
#pragma unroll
    for (int ff = 0; ff < NF1; ++ff) acc = fmaf(av[ff], W2s[ff * NF2 + g], acc);
    z[j] = acc;
    m = fmaxf(m, acc);
  }
  m = fmaxf(m, __shfl_xor(m, 1, 2));
  float s = 0.f;
#pragma unroll
  for (int j = 0; j < 20; ++j) s += __expf(z[j] - m);
  s += __shfl_xor(s, 1, 2);
  float ls = m + __logf(s);
  float4* orow = (float4*)(out + (size_t)v * NF2 + hw * 20);
#pragma unroll
  for (int q = 0; q < 5; ++q)
    orow[q] = make_float4(z[4 * q] - ls, z[4 * q + 1] - ls,
                          z[4 * q + 2] - ls, z[4 * q + 3] - ls);
}

extern "C" void kernel_launch(void* const* d_in, const int* in_sizes, int n_in,
                              void* d_out, int out_size, void* d_ws, size_t ws_size,
                              hipStream_t stream) {
  const float* x  = (const float*)d_in[0];
  const int*   ei = (const int*)d_in[1];
  const float* W1 = (const float*)d_in[2];
  const float* b1 = (const float*)d_in[3];
  const float* W2 = (const float*)d_in[4];
  const float* b2 = (const float*)d_in[5];
  int n = in_sizes[0] / NFEAT_IN;  // 100000
  int E = in_sizes[1] / 2;         // 3200000
  const int* src = ei;
  const int* dst = ei + E;
  float* out = (float*)d_out;
  int nbk = ((n - 1) >> BK_LG) + 1;   // 391
  int ntiles = n >> 4;                // 6250
  int n2 = n * 2;

  char* ws = (char*)d_ws;
  size_t off = 0;
  auto alloc = [&](size_t bytes) { size_t o = off; off = (off + bytes + 63) & ~63ULL; return o; };
  int*   gbsz = (int*)(ws + alloc(512 * 4));
  int*   boff = (int*)(ws + alloc(513 * 4));
  int*   gcur = (int*)(ws + alloc(512 * 4));
  int*   rp   = (int*)(ws + alloc((size_t)(n + 1) * 4));
  float* dinv = (float*)(ws + alloc((size_t)n * 4));
  unsigned int* ebuf = (unsigned int*)(ws + alloc((size_t)E * 4));
  int*   esrc = (int*)(ws + alloc((size_t)E * 4));
  __half* h1s = (__half*)(ws + alloc((size_t)n * NF1 * 2));
  __half* as2 = (__half*)(ws + alloc((size_t)n * NF1 * 2));

  hipMemsetAsync(gbsz, 0, 512 * 4, stream);

  k_bhist<<<1024, 256, 0, stream>>>(dst, gbsz, E, nbk);
  k_scanb<<<1, 512, 0, stream>>>(gbsz, boff, gcur, rp, nbk, n, E);
  k_part <<<1024, 256, 0, stream>>>(src, dst, gcur, ebuf, E, nbk);
  k_sortb<<<nbk, 1024, 0, stream>>>(ebuf, boff, esrc, rp, dinv, n);
  k_gemm1<<<(ntiles + 3) / 4, 256, 0, stream>>>(x, W1, dinv, h1s, ntiles);
  k_agg1 <<<(n2 + 255) / 256, 256, 0, stream>>>(rp, esrc, h1s, dinv, b1, as2, n2);
  k_agg2fin<<<(n2 + 255) / 256, 256, 0, stream>>>(rp, esrc, as2, dinv, W2, b2, out, n2);
}